// Round 4
// baseline (6310.532 us; speedup 1.0000x reference)
//
#include <hip/hip_runtime.h>

#define TT 512
#define BB 256
#define HH 512
#define DD 105
#define RS 85
#define NRULE 20
#define NOUT 33
#define HALF 256

#define NFRAG_REC 512              // 32 mtiles x 16 ktiles
#define NFRAG_IN  128              // 32 mtiles x 4 ktiles (k padded 105->128)
#define NFRAG_OUT 48               // 3 mtiles (o padded 33->48) x 16 ktiles
#define FRAG_IN_OFF  (NFRAG_REC)
#define FRAG_OUT_OFF (NFRAG_REC + NFRAG_IN)
#define NFRAG_TOT (NFRAG_REC + NFRAG_IN + NFRAG_OUT)

#define WP_BYTES   ((size_t)NFRAG_TOT * 1024)          // 704512
#define HX_OFF     WP_BYTES
#define HX_STRIDE  ((size_t)2 * 16 * HALF * 2)         // 16 KB per block (2 bufs)
#define HX_BYTES   ((size_t)32 * HX_STRIDE)            // 512 KB
#define FLAGS_OFF  (HX_OFF + HX_BYTES)                 // ~1.21 MB total ws

typedef __bf16 bf16x8 __attribute__((ext_vector_type(8)));
typedef float  f32x4  __attribute__((ext_vector_type(4)));
typedef unsigned long long u64x2 __attribute__((ext_vector_type(2)));

__device__ __forceinline__ unsigned short f2bf(float f) {
  unsigned u = __builtin_bit_cast(unsigned, f);
  u += 0x7FFFu + ((u >> 16) & 1u);            // RNE
  return (unsigned short)(u >> 16);
}

// Pack Wrec*mask, [Ws|Wr] (k padded to 128), Wout (m padded to 48) into MFMA
// 16x16x32 A-frag layout: frag f, lane l holds M[mt*16+(l&15)][kt*32+(l>>4)*8+j]
__global__ void pack_weights(const float* __restrict__ Ws_w, const float* __restrict__ Wr_w,
                             const float* __restrict__ Wrec_w, const float* __restrict__ mask,
                             const float* __restrict__ Wout_w, unsigned short* __restrict__ wp)
{
  int gid = blockIdx.x * blockDim.x + threadIdx.x;
  if (gid >= NFRAG_TOT * 64) return;
  int f = gid >> 6, lane = gid & 63;
  int m16 = lane & 15, kg = lane >> 4;
  float v[8];
  if (f < NFRAG_REC) {
    int mt = f >> 4, kt = f & 15;
    int m = mt * 16 + m16, k0 = kt * 32 + kg * 8;
#pragma unroll
    for (int j = 0; j < 8; ++j) {
      int k = k0 + j;
      v[j] = Wrec_w[m * HH + k] * mask[m * HH + k];
    }
  } else if (f < FRAG_OUT_OFF) {
    int ff = f - FRAG_IN_OFF;
    int mt = ff >> 2, kt = ff & 3;
    int m = mt * 16 + m16, k0 = kt * 32 + kg * 8;
#pragma unroll
    for (int j = 0; j < 8; ++j) {
      int k = k0 + j;
      float val = 0.f;
      if (k < RS) val = Ws_w[m * RS + k];
      else if (k < DD) val = Wr_w[m * NRULE + (k - RS)];
      v[j] = val;
    }
  } else {
    int ff = f - FRAG_OUT_OFF;
    int mt = ff >> 4, kt = ff & 15;
    int m = mt * 16 + m16, k0 = kt * 32 + kg * 8;
#pragma unroll
    for (int j = 0; j < 8; ++j) {
      int k = k0 + j;
      v[j] = (m < NOUT) ? Wout_w[m * HH + k] : 0.f;
    }
  }
  unsigned o[4];
#pragma unroll
  for (int j = 0; j < 4; ++j)
    o[j] = (unsigned)f2bf(v[2 * j]) | ((unsigned)f2bf(v[2 * j + 1]) << 16);
  uint4 st = make_uint4(o[0], o[1], o[2], o[3]);
  *reinterpret_cast<uint4*>(wp + (size_t)f * 512 + lane * 8) = st;
}

// 32 blocks: group g = bid&15 (16 batch rows), half hf = bid>>4 (256 h-rows).
// All weights resident per block: Wrec half-slice in AGPRs (2 mt/wave = 128),
// Win half in LDS (64 KB), Wout in LDS for out-duty blocks (48 KB).
// Pair exchange: relaxed agent-scope u64 atomics (no acquire/release cache
// maintenance); partner h consumed directly as MFMA B-frags from hx.
__global__ __launch_bounds__(512, 2)
void rnn_fused(const float* __restrict__ x, const float* __restrict__ noise,
               const float* __restrict__ Ws_b, const float* __restrict__ Wrec_b,
               const float* __restrict__ Wout_b, unsigned char* __restrict__ ws,
               float* __restrict__ out)
{
  __shared__ unsigned short h_lds[16 * HALF];       // own half, [b][hloc] bf16 swz (8 KB)
  __shared__ unsigned short x_lds[2][16 * 128];     // [b][k] bf16 swz (8 KB)
  __shared__ unsigned short win_lds[64 * 512];      // 64 input-W frags (64 KB)
  __shared__ unsigned short wout_lds[48 * 512];     // 48 out-W frags (48 KB, duty only)

  const int tid  = threadIdx.x;
  const int wv   = tid >> 6;
  const int lane = tid & 63;
  const int bcol = lane & 15;
  const int krow = lane >> 4;
  const int bid  = blockIdx.x;
  const int g    = bid & 15;
  const int hf   = bid >> 4;                         // 0 or 1
  const int gb   = g * 16;
  const int hbase = hf * HALF;
  const int sw   = (bcol & 7) << 3;                  // short-index XOR (16B granule)
  const bool outduty = (hf == 0);

  const uint4* wp4 = reinterpret_cast<const uint4*>(ws);
  unsigned long long* hx_own =
      (unsigned long long*)(ws + HX_OFF + (size_t)bid * HX_STRIDE);
  unsigned long long* hx_par =
      (unsigned long long*)(ws + HX_OFF + (size_t)(bid ^ 16) * HX_STRIDE);
  int* flags = (int*)(ws + FLAGS_OFF);

  // zero LDS state
  for (int i = tid; i < 16 * HALF; i += 512) h_lds[i] = 0;
  {
    unsigned short* xz = &x_lds[0][0];
    for (int i = tid; i < 2 * 16 * 128; i += 512) xz[i] = 0;
  }
  // stage Win half-slice (64 frags) into LDS
  for (int c = tid; c < 64 * 64; c += 512) {
    int fl = c >> 6, l = c & 63;
    uint4 w = wp4[(FRAG_IN_OFF + hf * 64 + fl) * 64 + l];
    *reinterpret_cast<uint4*>(&win_lds[fl * 512 + l * 8]) = w;
  }
  // stage Wout frags (48) for out-duty blocks
  if (outduty) {
    for (int c = tid; c < 48 * 64; c += 512) {
      int fl = c >> 6, l = c & 63;
      uint4 w = wp4[(FRAG_OUT_OFF + fl) * 64 + l];
      *reinterpret_cast<uint4*>(&wout_lds[fl * 512 + l * 8]) = w;
    }
  }

  // Wrec slice: 2 mtiles per wave (full k = 16 ktiles) -> AGPR-resident (128)
  bf16x8 wreg[2][16];
#pragma unroll
  for (int j = 0; j < 2; ++j)
#pragma unroll
    for (int kt = 0; kt < 16; ++kt)
      wreg[j][kt] = __builtin_bit_cast(bf16x8,
          wp4[((hf * 16 + 2 * wv + j) * 16 + kt) * 64 + lane]);

  float bias_reg[2][4];
#pragma unroll
  for (int j = 0; j < 2; ++j)
#pragma unroll
    for (int r = 0; r < 4; ++r) {
      int h = hbase + (2 * wv + j) * 16 + krow * 4 + r;
      bias_reg[j][r] = Ws_b[h] + Wrec_b[h];
    }
  float woutb[4];
#pragma unroll
  for (int r = 0; r < 4; ++r) {
    int o = wv * 16 + krow * 4 + r;
    woutb[r] = (outduty && wv < 3 && o < NOUT) ? Wout_b[o] : 0.f;
  }

  float hreg[2][4] = {};
  f32x4 nrA[2], nrB[2];

  __syncthreads();

  // stage t = 0
  if (tid < 420) {
    f32x4 xv = reinterpret_cast<const f32x4*>(x + (size_t)gb * DD)[tid];
#pragma unroll
    for (int j = 0; j < 4; ++j) {
      int e = tid * 4 + j;
      int b = e / DD, k = e - b * DD;
      x_lds[0][b * 128 + (k ^ ((b & 7) << 3))] = f2bf(xv[j]);
    }
  }
  {
    const float* nb = noise + ((size_t)gb + bcol) * HH + hbase + krow * 4;
#pragma unroll
    for (int j = 0; j < 2; ++j)
      nrA[j] = *reinterpret_cast<const f32x4*>(nb + (2 * wv + j) * 16);
  }
  __syncthreads();

#pragma unroll 1
  for (int t = 0; t < TT; ++t) {
    const int cur = t & 1;
    // ---------- P1a: own-half work (overlaps partner flag/data flight) ------
    f32x4 xs = {0.f, 0.f, 0.f, 0.f};
    if (t + 1 < TT) {
      if (tid < 420)
        xs = reinterpret_cast<const f32x4*>(x + ((size_t)(t + 1) * BB + gb) * DD)[tid];
      const float* nb = noise + (((size_t)(t + 1)) * BB + gb + bcol) * HH + hbase + krow * 4;
#pragma unroll
      for (int j = 0; j < 2; ++j)
        nrB[j] = *reinterpret_cast<const f32x4*>(nb + (2 * wv + j) * 16);
    }

    f32x4 acc[2];
    acc[0] = f32x4{0.f, 0.f, 0.f, 0.f};
    acc[1] = f32x4{0.f, 0.f, 0.f, 0.f};
    f32x4 po = {0.f, 0.f, 0.f, 0.f};

    // own-k recurrent MFMAs (h[t-1] own half from LDS; k-tiles hf*8..hf*8+7)
#pragma unroll
    for (int kto = 0; kto < 8; ++kto) {
      int k0 = kto * 32 + krow * 8;
      bf16x8 hb = __builtin_bit_cast(bf16x8,
          *reinterpret_cast<const uint4*>(&h_lds[bcol * HALF + (k0 ^ sw)]));
      int kt = hf * 8 + kto;
      acc[0] = __builtin_amdgcn_mfma_f32_16x16x32_bf16(wreg[0][kt], hb, acc[0], 0, 0, 0);
      acc[1] = __builtin_amdgcn_mfma_f32_16x16x32_bf16(wreg[1][kt], hb, acc[1], 0, 0, 0);
      if (outduty && wv < 3) {
        bf16x8 ao = __builtin_bit_cast(bf16x8,
            *reinterpret_cast<const uint4*>(&wout_lds[(wv * 16 + kt) * 512 + lane * 8]));
        po = __builtin_amdgcn_mfma_f32_16x16x32_bf16(ao, hb, po, 0, 0, 0);
      }
    }
    // input GEMM (Win half from LDS)
#pragma unroll
    for (int kx = 0; kx < 4; ++kx) {
      int k0 = kx * 32 + krow * 8;
      bf16x8 xb = __builtin_bit_cast(bf16x8,
          *reinterpret_cast<const uint4*>(&x_lds[cur][bcol * 128 + (k0 ^ sw)]));
#pragma unroll
      for (int j = 0; j < 2; ++j) {
        bf16x8 aw = __builtin_bit_cast(bf16x8,
            *reinterpret_cast<const uint4*>(&win_lds[((2 * wv + j) * 4 + kx) * 512 + lane * 8]));
        acc[j] = __builtin_amdgcn_mfma_f32_16x16x32_bf16(aw, xb, acc[j], 0, 0, 0);
      }
    }

    // ---------- P1b: partner half, consumed straight from hx ---------------
    if (t > 0) {
      if (lane == 0) {
        while (__hip_atomic_load(&flags[bid ^ 16], __ATOMIC_RELAXED,
                                 __HIP_MEMORY_SCOPE_AGENT) < t)
          __builtin_amdgcn_s_sleep(1);
      }
      const unsigned long long* hxp =
          hx_par + ((size_t)((t - 1) & 1) * 1024) + bcol * 64 + krow * 2;
#pragma unroll
      for (int half2 = 0; half2 < 2; ++half2) {
        unsigned long long pf[8];
#pragma unroll
        for (int q = 0; q < 4; ++q) {
          int kto = half2 * 4 + q;
          pf[2 * q]     = __hip_atomic_load(hxp + kto * 8, __ATOMIC_RELAXED,
                                            __HIP_MEMORY_SCOPE_AGENT);
          pf[2 * q + 1] = __hip_atomic_load(hxp + kto * 8 + 1, __ATOMIC_RELAXED,
                                            __HIP_MEMORY_SCOPE_AGENT);
        }
#pragma unroll
        for (int q = 0; q < 4; ++q) {
          int kt = (1 - hf) * 8 + half2 * 4 + q;
          bf16x8 hb = __builtin_bit_cast(bf16x8, u64x2{pf[2 * q], pf[2 * q + 1]});
          acc[0] = __builtin_amdgcn_mfma_f32_16x16x32_bf16(wreg[0][kt], hb, acc[0], 0, 0, 0);
          acc[1] = __builtin_amdgcn_mfma_f32_16x16x32_bf16(wreg[1][kt], hb, acc[1], 0, 0, 0);
          if (outduty && wv < 3) {
            bf16x8 ao = __builtin_bit_cast(bf16x8,
                *reinterpret_cast<const uint4*>(&wout_lds[(wv * 16 + kt) * 512 + lane * 8]));
            po = __builtin_amdgcn_mfma_f32_16x16x32_bf16(ao, hb, po, 0, 0, 0);
          }
        }
      }
      // store out[t-1]
      if (outduty && wv < 3) {
#pragma unroll
        for (int r = 0; r < 4; ++r) {
          int o = wv * 16 + krow * 4 + r;
          if (o < NOUT)
            out[((size_t)(t - 1) * BB + gb + bcol) * NOUT + o] = po[r] + woutb[r];
        }
      }
    }
    __syncthreads();   // all P1a reads of h_lds / x_lds[cur] done
    // ---------- P2: state update + publish ----------------------------------
#pragma unroll
    for (int j = 0; j < 2; ++j) {
      unsigned short hs[4];
#pragma unroll
      for (int r = 0; r < 4; ++r) {
        float v = acc[j][r] + bias_reg[j][r] + 0.05f * nrA[j][r];
        v = fmaxf(v, 0.f);
        float hn = 0.2f * v + 0.8f * hreg[j][r];
        hreg[j][r] = hn;
        hs[r] = f2bf(hn);
      }
      unsigned long long pk = (unsigned long long)hs[0]
                            | ((unsigned long long)hs[1] << 16)
                            | ((unsigned long long)hs[2] << 32)
                            | ((unsigned long long)hs[3] << 48);
      __hip_atomic_store(hx_own + (size_t)cur * 1024 + bcol * 64 + (2 * wv + j) * 4 + krow,
                         pk, __ATOMIC_RELAXED, __HIP_MEMORY_SCOPE_AGENT);
      int hloc = (2 * wv + j) * 16 + krow * 4;
      *reinterpret_cast<ushort4*>(&h_lds[bcol * HALF + (hloc ^ sw)]) =
          make_ushort4(hs[0], hs[1], hs[2], hs[3]);
    }
    if (t + 1 < TT && tid < 420) {
#pragma unroll
      for (int j = 0; j < 4; ++j) {
        int e = tid * 4 + j;
        int b = e / DD, k = e - b * DD;
        x_lds[cur ^ 1][b * 128 + (k ^ ((b & 7) << 3))] = f2bf(xs[j]);
      }
    }
#pragma unroll
    for (int j = 0; j < 2; ++j) nrA[j] = nrB[j];
    __syncthreads();   // h[t] in LDS + hx stores drained (vmcnt(0) at barrier)
    if (tid == 0)
      __hip_atomic_store(&flags[bid], t + 1, __ATOMIC_RELAXED, __HIP_MEMORY_SCOPE_AGENT);
  }

  // final out for t = TT-1 (own half from h_lds, partner from hx)
  if (outduty && wv < 3) {
    f32x4 po = {0.f, 0.f, 0.f, 0.f};
#pragma unroll
    for (int kto = 0; kto < 8; ++kto) {
      int k0 = kto * 32 + krow * 8;
      bf16x8 hb = __builtin_bit_cast(bf16x8,
          *reinterpret_cast<const uint4*>(&h_lds[bcol * HALF + (k0 ^ sw)]));
      int kt = hf * 8 + kto;
      bf16x8 ao = __builtin_bit_cast(bf16x8,
          *reinterpret_cast<const uint4*>(&wout_lds[(wv * 16 + kt) * 512 + lane * 8]));
      po = __builtin_amdgcn_mfma_f32_16x16x32_bf16(ao, hb, po, 0, 0, 0);
    }
    if (lane == 0) {
      while (__hip_atomic_load(&flags[bid ^ 16], __ATOMIC_RELAXED,
                               __HIP_MEMORY_SCOPE_AGENT) < TT)
        __builtin_amdgcn_s_sleep(1);
    }
    const unsigned long long* hxp =
        hx_par + ((size_t)((TT - 1) & 1) * 1024) + bcol * 64 + krow * 2;
#pragma unroll
    for (int kto = 0; kto < 8; ++kto) {
      unsigned long long p0 = __hip_atomic_load(hxp + kto * 8, __ATOMIC_RELAXED,
                                                __HIP_MEMORY_SCOPE_AGENT);
      unsigned long long p1 = __hip_atomic_load(hxp + kto * 8 + 1, __ATOMIC_RELAXED,
                                                __HIP_MEMORY_SCOPE_AGENT);
      int kt = (1 - hf) * 8 + kto;
      bf16x8 hb = __builtin_bit_cast(bf16x8, u64x2{p0, p1});
      bf16x8 ao = __builtin_bit_cast(bf16x8,
          *reinterpret_cast<const uint4*>(&wout_lds[(wv * 16 + kt) * 512 + lane * 8]));
      po = __builtin_amdgcn_mfma_f32_16x16x32_bf16(ao, hb, po, 0, 0, 0);
    }
#pragma unroll
    for (int r = 0; r < 4; ++r) {
      int o = wv * 16 + krow * 4 + r;
      if (o < NOUT)
        out[((size_t)(TT - 1) * BB + gb + bcol) * NOUT + o] = po[r] + woutb[r];
    }
  }
}

extern "C" void kernel_launch(void* const* d_in, const int* in_sizes, int n_in,
                              void* d_out, int out_size, void* d_ws, size_t ws_size,
                              hipStream_t stream) {
  (void)in_sizes; (void)n_in; (void)out_size; (void)ws_size;
  const float* x      = (const float*)d_in[0];
  const float* noise  = (const float*)d_in[1];
  const float* Ws_w   = (const float*)d_in[2];
  const float* Ws_b   = (const float*)d_in[3];
  const float* Wr_w   = (const float*)d_in[4];
  const float* Wrec_w = (const float*)d_in[5];
  const float* Wrec_b = (const float*)d_in[6];
  const float* mask   = (const float*)d_in[7];
  const float* Wout_w = (const float*)d_in[8];
  const float* Wout_b = (const float*)d_in[9];
  unsigned char* ws   = (unsigned char*)d_ws;        // needs ~1.22 MB
  float* out          = (float*)d_out;

  // reset handshake flags each launch (graph-replay safe)
  hipMemsetAsync(ws + FLAGS_OFF, 0, 32 * sizeof(int), stream);
  pack_weights<<<(NFRAG_TOT * 64 + 255) / 256, 256, 0, stream>>>(
      Ws_w, Wr_w, Wrec_w, mask, Wout_w, (unsigned short*)ws);
  rnn_fused<<<32, 512, 0, stream>>>(x, noise, Ws_b, Wrec_b, Wout_b, ws, out);
}

// Round 7
// 2752.123 us; speedup vs baseline: 2.2930x; 2.2930x over previous
//
#include <hip/hip_runtime.h>

#define TT 512
#define BB 256
#define HH 512
#define DD 105
#define RS 85
#define NRULE 20
#define NOUT 33
#define HALF 256

#define NFRAG_REC 512              // 32 mtiles x 16 ktiles
#define NFRAG_IN  128              // 32 mtiles x 4 ktiles (k padded 105->128)
#define NFRAG_OUT 48               // 3 mtiles (o padded 33->48) x 16 ktiles
#define FRAG_IN_OFF  (NFRAG_REC)
#define FRAG_OUT_OFF (NFRAG_REC + NFRAG_IN)
#define NFRAG_TOT (NFRAG_REC + NFRAG_IN + NFRAG_OUT)

#define WP_BYTES    ((size_t)NFRAG_TOT * 1024)         // 704512
#define PREC_OFF    WP_BYTES
#define PREC_STRIDE ((size_t)32768)                    // 2 parity slots x 16 KB
#define POUT_OFF    (PREC_OFF + 32 * PREC_STRIDE)
#define POUT_STRIDE ((size_t)9216)                     // 3 slots (par0,par1,tail) x 3 KB
#define EXCH_BYTES  (32 * PREC_STRIDE + 16 * POUT_STRIDE)

#define RETRY_GUARD 100000

typedef __bf16 bf16x8 __attribute__((ext_vector_type(8)));
typedef float  f32x4  __attribute__((ext_vector_type(4)));
typedef unsigned long long u64;

__device__ __forceinline__ unsigned short f2bf(float f) {
  unsigned u = __builtin_bit_cast(unsigned, f);
  u += 0x7FFFu + ((u >> 16) & 1u);            // RNE
  return (unsigned short)(u >> 16);
}
__device__ __forceinline__ u64 ld_agent(const u64* p) {
  return __hip_atomic_load(p, __ATOMIC_RELAXED, __HIP_MEMORY_SCOPE_AGENT);
}
__device__ __forceinline__ void st_agent(u64* p, u64 v) {
  __hip_atomic_store(p, v, __ATOMIC_RELAXED, __HIP_MEMORY_SCOPE_AGENT);
}
__device__ __forceinline__ float bfhi(unsigned w) {     // tagged u32 -> f32 value
  return __builtin_bit_cast(float, w & 0xffff0000u);
}
__device__ __forceinline__ unsigned pkv(float v, unsigned tag) {
  return ((unsigned)f2bf(v) << 16) | tag;
}
__device__ __forceinline__ int tags4_ok(u64 v0, u64 v1, u64 v2, u64 v3, unsigned tag) {
  return (((unsigned)v0 & 0xffffu) == tag) & (((unsigned)(v0 >> 32) & 0xffffu) == tag)
       & (((unsigned)v1 & 0xffffu) == tag) & (((unsigned)(v1 >> 32) & 0xffffu) == tag)
       & (((unsigned)v2 & 0xffffu) == tag) & (((unsigned)(v2 >> 32) & 0xffffu) == tag)
       & (((unsigned)v3 & 0xffffu) == tag) & (((unsigned)(v3 >> 32) & 0xffffu) == tag);
}
__device__ __forceinline__ int tags2_ok(u64 v0, u64 v1, unsigned tag) {
  return (((unsigned)v0 & 0xffffu) == tag) & (((unsigned)(v0 >> 32) & 0xffffu) == tag)
       & (((unsigned)v1 & 0xffffu) == tag) & (((unsigned)(v1 >> 32) & 0xffffu) == tag);
}

// Pack Wrec*mask, [Ws|Wr] (k padded to 128), Wout (m padded to 48) into MFMA
// 16x16x32 A-frag layout: frag f, lane l holds M[mt*16+(l&15)][kt*32+(l>>4)*8+j]
__global__ void pack_weights(const float* __restrict__ Ws_w, const float* __restrict__ Wr_w,
                             const float* __restrict__ Wrec_w, const float* __restrict__ mask,
                             const float* __restrict__ Wout_w, unsigned short* __restrict__ wp)
{
  int gid = blockIdx.x * blockDim.x + threadIdx.x;
  if (gid >= NFRAG_TOT * 64) return;
  int f = gid >> 6, lane = gid & 63;
  int m16 = lane & 15, kg = lane >> 4;
  float v[8];
  if (f < NFRAG_REC) {
    int mt = f >> 4, kt = f & 15;
    int m = mt * 16 + m16, k0 = kt * 32 + kg * 8;
#pragma unroll
    for (int j = 0; j < 8; ++j) {
      int k = k0 + j;
      v[j] = Wrec_w[m * HH + k] * mask[m * HH + k];
    }
  } else if (f < FRAG_OUT_OFF) {
    int ff = f - FRAG_IN_OFF;
    int mt = ff >> 2, kt = ff & 3;
    int m = mt * 16 + m16, k0 = kt * 32 + kg * 8;
#pragma unroll
    for (int j = 0; j < 8; ++j) {
      int k = k0 + j;
      float val = 0.f;
      if (k < RS) val = Ws_w[m * RS + k];
      else if (k < DD) val = Wr_w[m * NRULE + (k - RS)];
      v[j] = val;
    }
  } else {
    int ff = f - FRAG_OUT_OFF;
    int mt = ff >> 4, kt = ff & 15;
    int m = mt * 16 + m16, k0 = kt * 32 + kg * 8;
#pragma unroll
    for (int j = 0; j < 8; ++j) {
      int k = k0 + j;
      v[j] = (m < NOUT) ? Wout_w[m * HH + k] : 0.f;
    }
  }
  unsigned o[4];
#pragma unroll
  for (int j = 0; j < 4; ++j)
    o[j] = (unsigned)f2bf(v[2 * j]) | ((unsigned)f2bf(v[2 * j + 1]) << 16);
  uint4 st = make_uint4(o[0], o[1], o[2], o[3]);
  *reinterpret_cast<uint4*>(wp + (size_t)f * 512 + lane * 8) = st;
}

// 32 blocks: group g = bid&15 (16 batch rows), half hf = bid>>4 (256 h-rows +
// matching 256 k-cols of Wrec). Exchange = step-tagged bf16 partial sums
// (tag in low 16 bits of each u32; word atomicity -> self-validating).
// Parity double-buffered; pout publish gated after prec consume; tail slot
// dedicated -> no producer can clobber an unconsumed tag (deadlock-free).
__global__ __launch_bounds__(512, 2)
void rnn_fused(const float* __restrict__ x, const float* __restrict__ noise,
               const float* __restrict__ Ws_b, const float* __restrict__ Wrec_b,
               const float* __restrict__ Wout_b, unsigned char* __restrict__ ws,
               float* __restrict__ out)
{
  __shared__ alignas(16) unsigned short h_lds[16 * HALF];    // own h half (8 KB)
  __shared__ alignas(16) unsigned short x_lds[2][16 * 128];  // (8 KB)
  __shared__ alignas(16) unsigned short win_lds[64 * 512];   // own-half Win (64 KB)
  __shared__ alignas(16) unsigned short wout_lds[24 * 512];  // Wout own-k (24 KB)

  const int tid  = threadIdx.x;
  const int wv   = tid >> 6;
  const int lane = tid & 63;
  const int bcol = lane & 15;
  const int krow = lane >> 4;
  const int bid  = blockIdx.x;
  const int g    = bid & 15;
  const int hf   = bid >> 4;                         // 0 or 1
  const int gb   = g * 16;
  const int hbase = hf * HALF;
  const int sw   = (bcol & 7) << 3;
  const bool outduty = (hf == 0);

  const uint4* wp4 = reinterpret_cast<const uint4*>(ws);
  u64* prec_own = (u64*)(ws + PREC_OFF + (size_t)bid * PREC_STRIDE);
  const u64* prec_par = (const u64*)(ws + PREC_OFF + (size_t)(bid ^ 16) * PREC_STRIDE);
  u64* pout_buf = (u64*)(ws + POUT_OFF + (size_t)g * POUT_STRIDE);

  // zero LDS state
  for (int i = tid; i < 16 * HALF; i += 512) h_lds[i] = 0;
  {
    unsigned short* xz = &x_lds[0][0];
    for (int i = tid; i < 2 * 16 * 128; i += 512) xz[i] = 0;
  }
  // stage Win own half (64 frags) into LDS
  for (int c = tid; c < 64 * 64; c += 512) {
    int fl = c >> 6, l = c & 63;
    uint4 w = wp4[(FRAG_IN_OFF + hf * 64 + fl) * 64 + l];
    *reinterpret_cast<uint4*>(&win_lds[fl * 512 + l * 8]) = w;
  }
  // stage Wout own-k (3 mt x 8 kt = 24 frags)
  for (int c = tid; c < 24 * 64; c += 512) {
    int fl = c >> 6, l = c & 63;
    int mt_o = fl >> 3, kto = fl & 7;
    uint4 w = wp4[(FRAG_OUT_OFF + mt_o * 16 + hf * 8 + kto) * 64 + l];
    *reinterpret_cast<uint4*>(&wout_lds[fl * 512 + l * 8]) = w;
  }

  // Wrec: own-m x own-k (16 frags) + partner-m x own-k (16 frags) per wave
  bf16x8 wreg_own[2][8], wreg_par[2][8];
#pragma unroll
  for (int j = 0; j < 2; ++j)
#pragma unroll
    for (int kt = 0; kt < 8; ++kt) {
      wreg_own[j][kt] = __builtin_bit_cast(bf16x8,
          wp4[((hf * 16 + 2 * wv + j) * 16 + (hf * 8 + kt)) * 64 + lane]);
      wreg_par[j][kt] = __builtin_bit_cast(bf16x8,
          wp4[(((1 - hf) * 16 + 2 * wv + j) * 16 + (hf * 8 + kt)) * 64 + lane]);
    }

  float bias_reg[2][4];
#pragma unroll
  for (int j = 0; j < 2; ++j)
#pragma unroll
    for (int r = 0; r < 4; ++r) {
      int h = hbase + (2 * wv + j) * 16 + krow * 4 + r;
      bias_reg[j][r] = Ws_b[h] + Wrec_b[h];
    }
  float woutb[4];
#pragma unroll
  for (int r = 0; r < 4; ++r) {
    int o = wv * 16 + krow * 4 + r;
    woutb[r] = (outduty && wv < 3 && o < NOUT) ? Wout_b[o] : 0.f;
  }

  // exchange addressing (symmetric producer/consumer formulas)
  const int rbase = bcol * 256 + 2 * wv * 16 + krow * 4;   // u32 index
  const int ri = rbase >> 1;                               // u64 index (j=0); j=1: +8
  const int oi = (bcol * 48 + wv * 16 + krow * 4) >> 1;    // u64 index (wv<3)

  float hreg[2][4] = {};
  f32x4 nrA[2], nrB[2];
  f32x4 po_hold = {0.f, 0.f, 0.f, 0.f};

  __syncthreads();

  // stage t = 0
  if (tid < 420) {
    f32x4 xv = reinterpret_cast<const f32x4*>(x + (size_t)gb * DD)[tid];
#pragma unroll
    for (int j = 0; j < 4; ++j) {
      int e = tid * 4 + j;
      int b = e / DD, k = e - b * DD;
      x_lds[0][b * 128 + (k ^ ((b & 7) << 3))] = f2bf(xv[j]);
    }
  }
  {
    const float* nb = noise + ((size_t)gb + bcol) * HH + hbase + krow * 4;
#pragma unroll
    for (int j = 0; j < 2; ++j)
      nrA[j] = *reinterpret_cast<const f32x4*>(nb + (2 * wv + j) * 16);
  }
  __syncthreads();

#pragma unroll 1
  for (int t = 0; t < TT; ++t) {
    const int cur = t & 1;
    const unsigned tag = (unsigned)t;
    u64* prec_slot = prec_own + (size_t)(t & 1) * 2048;
    const u64* precp_slot = prec_par + (size_t)(t & 1) * 2048;
    // -- prefetch t+1 inputs ------------------------------------------------
    f32x4 xs = {0.f, 0.f, 0.f, 0.f};
    if (t + 1 < TT) {
      if (tid < 420)
        xs = reinterpret_cast<const f32x4*>(x + ((size_t)(t + 1) * BB + gb) * DD)[tid];
      const float* nb = noise + (((size_t)(t + 1)) * BB + gb + bcol) * HH + hbase + krow * 4;
#pragma unroll
      for (int j = 0; j < 2; ++j)
        nrB[j] = *reinterpret_cast<const f32x4*>(nb + (2 * wv + j) * 16);
    }

    // -- publish partial for partner: W[m par][k own] . h_own[t-1] ----------
    if (t > 0) {
      f32x4 pc0 = {0.f,0.f,0.f,0.f}, pc1 = {0.f,0.f,0.f,0.f};
#pragma unroll
      for (int kto = 0; kto < 8; ++kto) {
        int k0 = kto * 32 + krow * 8;
        bf16x8 hb = __builtin_bit_cast(bf16x8,
            *reinterpret_cast<const uint4*>(&h_lds[bcol * HALF + (k0 ^ sw)]));
        pc0 = __builtin_amdgcn_mfma_f32_16x16x32_bf16(wreg_par[0][kto], hb, pc0, 0, 0, 0);
        pc1 = __builtin_amdgcn_mfma_f32_16x16x32_bf16(wreg_par[1][kto], hb, pc1, 0, 0, 0);
      }
      st_agent(prec_slot + ri,     (u64)pkv(pc0[0], tag) | ((u64)pkv(pc0[1], tag) << 32));
      st_agent(prec_slot + ri + 1, (u64)pkv(pc0[2], tag) | ((u64)pkv(pc0[3], tag) << 32));
      st_agent(prec_slot + ri + 8, (u64)pkv(pc1[0], tag) | ((u64)pkv(pc1[1], tag) << 32));
      st_agent(prec_slot + ri + 9, (u64)pkv(pc1[2], tag) | ((u64)pkv(pc1[3], tag) << 32));
    }

    // -- own recurrent + input GEMMs ----------------------------------------
    f32x4 acc[2];
    acc[0] = f32x4{0.f,0.f,0.f,0.f};
    acc[1] = f32x4{0.f,0.f,0.f,0.f};
#pragma unroll
    for (int kto = 0; kto < 8; ++kto) {
      int k0 = kto * 32 + krow * 8;
      bf16x8 hb = __builtin_bit_cast(bf16x8,
          *reinterpret_cast<const uint4*>(&h_lds[bcol * HALF + (k0 ^ sw)]));
      acc[0] = __builtin_amdgcn_mfma_f32_16x16x32_bf16(wreg_own[0][kto], hb, acc[0], 0, 0, 0);
      acc[1] = __builtin_amdgcn_mfma_f32_16x16x32_bf16(wreg_own[1][kto], hb, acc[1], 0, 0, 0);
    }
#pragma unroll
    for (int kx = 0; kx < 4; ++kx) {
      int k0 = kx * 32 + krow * 8;
      bf16x8 xb = __builtin_bit_cast(bf16x8,
          *reinterpret_cast<const uint4*>(&x_lds[cur][bcol * 128 + (k0 ^ sw)]));
#pragma unroll
      for (int j = 0; j < 2; ++j) {
        bf16x8 aw = __builtin_bit_cast(bf16x8,
            *reinterpret_cast<const uint4*>(&win_lds[((2 * wv + j) * 4 + kx) * 512 + lane * 8]));
        acc[j] = __builtin_amdgcn_mfma_f32_16x16x32_bf16(aw, xb, acc[j], 0, 0, 0);
      }
    }

    // -- out-partial over h[t-1] (own k-half) -------------------------------
    f32x4 po = {0.f, 0.f, 0.f, 0.f};
    if (t > 0 && wv < 3) {
#pragma unroll
      for (int kto = 0; kto < 8; ++kto) {
        int k0 = kto * 32 + krow * 8;
        bf16x8 hb = __builtin_bit_cast(bf16x8,
            *reinterpret_cast<const uint4*>(&h_lds[bcol * HALF + (k0 ^ sw)]));
        bf16x8 ao = __builtin_bit_cast(bf16x8,
            *reinterpret_cast<const uint4*>(&wout_lds[(wv * 8 + kto) * 512 + lane * 8]));
        po = __builtin_amdgcn_mfma_f32_16x16x32_bf16(ao, hb, po, 0, 0, 0);
      }
    }

    // -- consume partner's recurrent partial (tag-validated, guarded retry) --
    f32x4 pa0 = {0.f,0.f,0.f,0.f}, pa1 = {0.f,0.f,0.f,0.f};
    if (t > 0) {
      u64 v0, v1, v2, v3;
      int guard = RETRY_GUARD;
      for (;;) {
        v0 = ld_agent(precp_slot + ri);
        v1 = ld_agent(precp_slot + ri + 1);
        v2 = ld_agent(precp_slot + ri + 8);
        v3 = ld_agent(precp_slot + ri + 9);
        if (__all(tags4_ok(v0, v1, v2, v3, tag)) || --guard == 0) break;
        __builtin_amdgcn_s_sleep(1);
      }
      pa0[0] = bfhi((unsigned)v0); pa0[1] = bfhi((unsigned)(v0 >> 32));
      pa0[2] = bfhi((unsigned)v1); pa0[3] = bfhi((unsigned)(v1 >> 32));
      pa1[0] = bfhi((unsigned)v2); pa1[1] = bfhi((unsigned)(v2 >> 32));
      pa1[2] = bfhi((unsigned)v3); pa1[3] = bfhi((unsigned)(v3 >> 32));
      // -- pout publish AFTER prec consume (ordering gates the parity slots) --
      if (!outduty && wv < 3) {
        u64* ps = pout_buf + (size_t)(t & 1) * 384;
        st_agent(ps + oi,     (u64)pkv(po[0], tag) | ((u64)pkv(po[1], tag) << 32));
        st_agent(ps + oi + 1, (u64)pkv(po[2], tag) | ((u64)pkv(po[3], tag) << 32));
      }
    }

    __syncthreads();   // all h_lds / x_lds[cur] reads done

    // -- P2: state update + h_lds write + x stage ---------------------------
#pragma unroll
    for (int j = 0; j < 2; ++j) {
      unsigned short hs[4];
      f32x4 pa = j ? pa1 : pa0;
#pragma unroll
      for (int r = 0; r < 4; ++r) {
        float v = acc[j][r] + pa[r] + bias_reg[j][r] + 0.05f * nrA[j][r];
        v = fmaxf(v, 0.f);
        float hn = 0.2f * v + 0.8f * hreg[j][r];
        hreg[j][r] = hn;
        hs[r] = f2bf(hn);
      }
      int hloc = (2 * wv + j) * 16 + krow * 4;
      *reinterpret_cast<ushort4*>(&h_lds[bcol * HALF + (hloc ^ sw)]) =
          make_ushort4(hs[0], hs[1], hs[2], hs[3]);
    }
    if (t + 1 < TT && tid < 420) {
#pragma unroll
      for (int j = 0; j < 4; ++j) {
        int e = tid * 4 + j;
        int b = e / DD, k = e - b * DD;
        x_lds[cur ^ 1][b * 128 + (k ^ ((b & 7) << 3))] = f2bf(xs[j]);
      }
    }
#pragma unroll
    for (int j = 0; j < 2; ++j) nrA[j] = nrB[j];

    // -- duty: assemble out[t-2] from po_hold + partner pout(t-1) -----------
    if (outduty && wv < 3 && t >= 2) {
      const unsigned otag = (unsigned)(t - 1);
      const u64* ps = pout_buf + (size_t)((t - 1) & 1) * 384;
      u64 w0, w1;
      int guard = RETRY_GUARD;
      for (;;) {
        w0 = ld_agent(ps + oi);
        w1 = ld_agent(ps + oi + 1);
        if (__all(tags2_ok(w0, w1, otag)) || --guard == 0) break;
        __builtin_amdgcn_s_sleep(1);
      }
      float pr[4] = { bfhi((unsigned)w0), bfhi((unsigned)(w0 >> 32)),
                      bfhi((unsigned)w1), bfhi((unsigned)(w1 >> 32)) };
#pragma unroll
      for (int r = 0; r < 4; ++r) {
        int o = wv * 16 + krow * 4 + r;
        if (o < NOUT)
          out[((size_t)(t - 2) * BB + gb + bcol) * NOUT + o] = po_hold[r] + pr[r] + woutb[r];
      }
    }
    if (outduty && wv < 3 && t > 0) po_hold = po;

    __syncthreads();   // h[t] in LDS before next step's reads
  }

  // ---- tail ----------------------------------------------------------------
  if (!outduty && wv < 3) {
    // out-partial over h[TT-1] -> DEDICATED tail slot (never clobbered)
    f32x4 po = {0.f, 0.f, 0.f, 0.f};
#pragma unroll
    for (int kto = 0; kto < 8; ++kto) {
      int k0 = kto * 32 + krow * 8;
      bf16x8 hb = __builtin_bit_cast(bf16x8,
          *reinterpret_cast<const uint4*>(&h_lds[bcol * HALF + (k0 ^ sw)]));
      bf16x8 ao = __builtin_bit_cast(bf16x8,
          *reinterpret_cast<const uint4*>(&wout_lds[(wv * 8 + kto) * 512 + lane * 8]));
      po = __builtin_amdgcn_mfma_f32_16x16x32_bf16(ao, hb, po, 0, 0, 0);
    }
    const unsigned tagT = (unsigned)TT;
    u64* ps = pout_buf + (size_t)2 * 384;
    st_agent(ps + oi,     (u64)pkv(po[0], tagT) | ((u64)pkv(po[1], tagT) << 32));
    st_agent(ps + oi + 1, (u64)pkv(po[2], tagT) | ((u64)pkv(po[3], tagT) << 32));
  }
  if (outduty && wv < 3) {
    // out[TT-2]: po_hold (own, over h[TT-2]) + partner pout(TT-1) slot par1
    {
      const unsigned otag = (unsigned)(TT - 1);
      const u64* ps = pout_buf + (size_t)((TT - 1) & 1) * 384;
      u64 w0, w1;
      int guard = RETRY_GUARD;
      for (;;) {
        w0 = ld_agent(ps + oi);
        w1 = ld_agent(ps + oi + 1);
        if (__all(tags2_ok(w0, w1, otag)) || --guard == 0) break;
        __builtin_amdgcn_s_sleep(1);
      }
      float pr[4] = { bfhi((unsigned)w0), bfhi((unsigned)(w0 >> 32)),
                      bfhi((unsigned)w1), bfhi((unsigned)(w1 >> 32)) };
#pragma unroll
      for (int r = 0; r < 4; ++r) {
        int o = wv * 16 + krow * 4 + r;
        if (o < NOUT)
          out[((size_t)(TT - 2) * BB + gb + bcol) * NOUT + o] = po_hold[r] + pr[r] + woutb[r];
      }
    }
    // out[TT-1]: own fresh po over h[TT-1] + partner tail slot (tag TT)
    {
      f32x4 po = {0.f, 0.f, 0.f, 0.f};
#pragma unroll
      for (int kto = 0; kto < 8; ++kto) {
        int k0 = kto * 32 + krow * 8;
        bf16x8 hb = __builtin_bit_cast(bf16x8,
            *reinterpret_cast<const uint4*>(&h_lds[bcol * HALF + (k0 ^ sw)]));
        bf16x8 ao = __builtin_bit_cast(bf16x8,
            *reinterpret_cast<const uint4*>(&wout_lds[(wv * 8 + kto) * 512 + lane * 8]));
        po = __builtin_amdgcn_mfma_f32_16x16x32_bf16(ao, hb, po, 0, 0, 0);
      }
      const unsigned tagT = (unsigned)TT;
      const u64* ps = pout_buf + (size_t)2 * 384;
      u64 w0, w1;
      int guard = RETRY_GUARD;
      for (;;) {
        w0 = ld_agent(ps + oi);
        w1 = ld_agent(ps + oi + 1);
        if (__all(tags2_ok(w0, w1, tagT)) || --guard == 0) break;
        __builtin_amdgcn_s_sleep(1);
      }
      float pr[4] = { bfhi((unsigned)w0), bfhi((unsigned)(w0 >> 32)),
                      bfhi((unsigned)w1), bfhi((unsigned)(w1 >> 32)) };
#pragma unroll
      for (int r = 0; r < 4; ++r) {
        int o = wv * 16 + krow * 4 + r;
        if (o < NOUT)
          out[((size_t)(TT - 1) * BB + gb + bcol) * NOUT + o] = po[r] + pr[r] + woutb[r];
      }
    }
  }
}

extern "C" void kernel_launch(void* const* d_in, const int* in_sizes, int n_in,
                              void* d_out, int out_size, void* d_ws, size_t ws_size,
                              hipStream_t stream) {
  (void)in_sizes; (void)n_in; (void)out_size; (void)ws_size;
  const float* x      = (const float*)d_in[0];
  const float* noise  = (const float*)d_in[1];
  const float* Ws_w   = (const float*)d_in[2];
  const float* Ws_b   = (const float*)d_in[3];
  const float* Wr_w   = (const float*)d_in[4];
  const float* Wrec_w = (const float*)d_in[5];
  const float* Wrec_b = (const float*)d_in[6];
  const float* mask   = (const float*)d_in[7];
  const float* Wout_w = (const float*)d_in[8];
  const float* Wout_b = (const float*)d_in[9];
  unsigned char* ws   = (unsigned char*)d_ws;        // needs ~1.82 MB
  float* out          = (float*)d_out;

  // zero exchange tags each launch (poison/replay safe)
  hipMemsetAsync(ws + PREC_OFF, 0, EXCH_BYTES, stream);
  pack_weights<<<(NFRAG_TOT * 64 + 255) / 256, 256, 0, stream>>>(
      Ws_w, Wr_w, Wrec_w, mask, Wout_w, (unsigned short*)ws);
  rnn_fused<<<32, 512, 0, stream>>>(x, noise, Ws_b, Wrec_b, Wout_b, ws, out);
}